// Round 7
// baseline (495.181 us; speedup 1.0000x reference)
//
#include <hip/hip_runtime.h>

// ---------------------------------------------------------------------------
// GAT edge classifier, MI355X.
//   CSR build (deg hist -> scan -> scatter)            [int atomics only]
//   pack: x -> (xh, xl) bf16 split; W1,W2 -> transposed bf16 splits
//   GEMM  (templated NF): block = 4 waves x 64 rows, wave = 16 rows x 16*NF.
//         Manual double-buffered register prefetch (named buffers, fully
//         unrolled K) -- compiler alone would not pipeline (r5/r6: VGPR=32,
//         serialized loads, MfmaUtil 6%). 3-term bf16 split product.
//   attn node dots (bf16 reads)
//   gather1: 1 wave/node, 8B/lane, fused p=exp(lrelu(.)), 2-edge ILP
//   GEMM2 -> xp2b; attn2; gather2 (4-edge groups/wave, fused uv=h2@Wc)
//   classify: out[e] = u[row] + v[col] + bc
// ---------------------------------------------------------------------------

#define NEG 0.2f

typedef __attribute__((ext_vector_type(8))) short bf16x8;
typedef __attribute__((ext_vector_type(4))) float f32x4;

__device__ __forceinline__ unsigned short f2bf(float f) {
    unsigned int u = __float_as_uint(f);
    unsigned int r = (u + 0x7FFFu + ((u >> 16) & 1u)) >> 16;   // RNE
    return (unsigned short)r;
}
__device__ __forceinline__ float bf2f(unsigned short h) {
    return __uint_as_float(((unsigned int)h) << 16);
}
__device__ __forceinline__ float bflo(unsigned int u) { return __uint_as_float(u << 16); }
__device__ __forceinline__ float bfhi(unsigned int u) { return __uint_as_float(u & 0xFFFF0000u); }
__device__ __forceinline__ float lrelu(float x) { return x > 0.f ? x : NEG * x; }

// ------------------------------- CSR build --------------------------------

__global__ __launch_bounds__(256) void k_init(int* deg, int* cur, int n) {
    int i = blockIdx.x * 256 + threadIdx.x;
    if (i < n) { deg[i] = 1; cur[i] = 0; }  // deg starts at 1 for self-loop
}

__global__ __launch_bounds__(256) void k_hist(const int* __restrict__ ei, int* deg, int E) {
    int e = blockIdx.x * 256 + threadIdx.x;
    if (e < E) atomicAdd(&deg[ei[E + e]], 1);   // dst = ei[1][e]
}

__global__ __launch_bounds__(1024) void k_scan(const int* __restrict__ deg, int* __restrict__ rowptr, int n) {
    __shared__ int sums[1024];
    int t = threadIdx.x;
    int chunk = (n + 1023) >> 10;
    int lo = t * chunk, hi = min(lo + chunk, n);
    int s = 0;
    for (int i = lo; i < hi; i++) s += deg[i];
    sums[t] = s;
    __syncthreads();
    for (int off = 1; off < 1024; off <<= 1) {
        int v = (t >= off) ? sums[t - off] : 0;
        __syncthreads();
        sums[t] += v;
        __syncthreads();
    }
    int run = sums[t] - s;  // exclusive prefix at lo
    for (int i = lo; i < hi; i++) { rowptr[i] = run; run += deg[i]; }
    if (t == 1023) rowptr[n] = sums[1023];
}

__global__ __launch_bounds__(256) void k_scatter(const int* __restrict__ ei, const int* __restrict__ rowptr,
                                                 int* cur, int* csr_src, int E, int N) {
    int e = blockIdx.x * 256 + threadIdx.x;
    if (e < E) {
        int d = ei[E + e];
        int pos = rowptr[d] + atomicAdd(&cur[d], 1);
        csr_src[pos] = ei[e];
    } else if (e < E + N) {
        int i = e - E;  // self loop
        int pos = rowptr[i] + atomicAdd(&cur[i], 1);
        csr_src[pos] = i;
    }
}

// ------------------------------- packing ----------------------------------

__global__ __launch_bounds__(256) void k_pack_split(const float* __restrict__ src,
                                                    unsigned short* __restrict__ hi,
                                                    unsigned short* __restrict__ lo, long n4) {
    long i = (long)blockIdx.x * 256 + threadIdx.x;
    long stride = (long)gridDim.x * 256;
    for (; i < n4; i += stride) {
        float4 v = ((const float4*)src)[i];
        unsigned short h0 = f2bf(v.x), h1 = f2bf(v.y), h2 = f2bf(v.z), h3 = f2bf(v.w);
        ushort4 H = make_ushort4(h0, h1, h2, h3);
        ushort4 L = make_ushort4(f2bf(v.x - bf2f(h0)), f2bf(v.y - bf2f(h1)),
                                 f2bf(v.z - bf2f(h2)), f2bf(v.w - bf2f(h3)));
        ((ushort4*)hi)[i] = H;
        ((ushort4*)lo)[i] = L;
    }
}

// W [K,N] fp32 -> WT hi/lo bf16 [N,K]
__global__ __launch_bounds__(256) void k_pack_wT(const float* __restrict__ W,
                                                 unsigned short* __restrict__ hiT,
                                                 unsigned short* __restrict__ loT, int K, int N) {
    int t = blockIdx.x * 256 + threadIdx.x;
    if (t >= K * N) return;
    int n = t / K, k = t - n * K;
    float v = W[(size_t)k * N + n];
    unsigned short h = f2bf(v);
    hiT[t] = h;
    loT[t] = f2bf(v - bf2f(h));
}

// ------------------------------- MFMA GEMM --------------------------------
// C[M,N] = A[M,K] @ B[K,N]; A hi/lo bf16 row-major, B hi/lo bf16 [N,K].
// Block = 4 waves = 64 rows x 16*NF cols; grid.y tiles N. K fixed = 32*KCH.
// Manual double-buffer: named register buffers 0/1, fully unrolled K-loop
// (all compile-time indices -> no scratch, rule #20). While chunk c's MFMAs
// issue, chunk c+1's 2+2*NF loads are in flight in the other buffer.
// launch_bounds(256,2) -> 256 VGPR budget for both buffers (~190 used).
template<int NF, int KCH>
__global__ __launch_bounds__(256, 2) void k_mfma_gemmT(const unsigned short* __restrict__ Ah,
                                                       const unsigned short* __restrict__ Al,
                                                       const unsigned short* __restrict__ BhT,
                                                       const unsigned short* __restrict__ BlT,
                                                       unsigned short* __restrict__ Cb, int M, int N, int K) {
    int wv = threadIdx.x >> 6, l = threadIdx.x & 63;
    int r = l & 15, hk = l >> 4;
    int m0 = blockIdx.x * 64 + wv * 16;
    int n0 = blockIdx.y * (16 * NF);
    int arow = min(m0 + r, M - 1);
    const unsigned short* aph = Ah + (size_t)arow * K + hk * 8;
    const unsigned short* apl = Al + (size_t)arow * K + hk * 8;
    const unsigned short* bph = BhT + (size_t)(n0 + r) * K + hk * 8;
    const unsigned short* bpl = BlT + (size_t)(n0 + r) * K + hk * 8;

    f32x4 acc[NF];
#pragma unroll
    for (int nf = 0; nf < NF; nf++) acc[nf] = f32x4{0, 0, 0, 0};

    bf16x8 ah0, al0, bh0[NF], bl0[NF];
    bf16x8 ah1, al1, bh1[NF], bl1[NF];

    auto load = [&](int c, bf16x8& ah, bf16x8& al, bf16x8* bh, bf16x8* bl) {
        int k0 = c * 32;
        ah = *(const bf16x8*)(aph + k0);
        al = *(const bf16x8*)(apl + k0);
#pragma unroll
        for (int nf = 0; nf < NF; nf++) {
            bh[nf] = *(const bf16x8*)(bph + (size_t)nf * 16 * K + k0);
            bl[nf] = *(const bf16x8*)(bpl + (size_t)nf * 16 * K + k0);
        }
    };
    auto mfma = [&](const bf16x8& ah, const bf16x8& al, const bf16x8* bh, const bf16x8* bl) {
#pragma unroll
        for (int nf = 0; nf < NF; nf++) {
            acc[nf] = __builtin_amdgcn_mfma_f32_16x16x32_bf16(ah, bh[nf], acc[nf], 0, 0, 0);
            acc[nf] = __builtin_amdgcn_mfma_f32_16x16x32_bf16(ah, bl[nf], acc[nf], 0, 0, 0);
            acc[nf] = __builtin_amdgcn_mfma_f32_16x16x32_bf16(al, bh[nf], acc[nf], 0, 0, 0);
        }
    };

    load(0, ah0, al0, bh0, bl0);
#pragma unroll
    for (int c = 0; c < KCH; c++) {
        if ((c & 1) == 0) {
            if (c + 1 < KCH) load(c + 1, ah1, al1, bh1, bl1);
            mfma(ah0, al0, bh0, bl0);
        } else {
            if (c + 1 < KCH) load(c + 1, ah0, al0, bh0, bl0);
            mfma(ah1, al1, bh1, bl1);
        }
    }

#pragma unroll
    for (int nf = 0; nf < NF; nf++) {
#pragma unroll
        for (int j = 0; j < 4; j++) {
            int m = m0 + hk * 4 + j;
            if (m < M) Cb[(size_t)m * N + n0 + nf * 16 + r] = f2bf(acc[nf][j]);
        }
    }
}

// ------------------------------- attention --------------------------------

// a_src/a_dst[n,h] from bf16 xpb; H heads of C=64 channels, thread=(n,h)
__global__ __launch_bounds__(256) void k_attn(const unsigned short* __restrict__ xpb,
                                              const float* __restrict__ att_s,
                                              const float* __restrict__ att_d,
                                              float* __restrict__ as, float* __restrict__ ad,
                                              int M, int H) {
    int idx = blockIdx.x * 256 + threadIdx.x;
    if (idx >= M * H) return;
    int n = idx / H, h = idx - n * H;
    const uint4* row = (const uint4*)(xpb + (size_t)n * (64 * H) + h * 64);
    const float* fs = att_s + h * 64;
    const float* fd = att_d + h * 64;
    float s = 0.f, d = 0.f;
#pragma unroll
    for (int j = 0; j < 8; j++) {
        uint4 v = row[j];
        unsigned int uu[4] = {v.x, v.y, v.z, v.w};
#pragma unroll
        for (int q = 0; q < 4; q++) {
            float lo = bflo(uu[q]);
            float hi = bfhi(uu[q]);
            int c = j * 8 + q * 2;
            s += lo * fs[c] + hi * fs[c + 1];
            d += lo * fd[c] + hi * fd[c + 1];
        }
    }
    as[idx] = s; ad[idx] = d;
}

// gather layer 1: 1 wave/node, lane owns 4 cols (8B), head h=lane>>4.
// p computed inline from as/ad (no max-sub: raw is O(3), exp safe in fp32).
__global__ __launch_bounds__(256) void k_gather1(const unsigned short* __restrict__ xpb,
                                                 const float* __restrict__ as, const float* __restrict__ ad,
                                                 const int* __restrict__ rowptr, const int* __restrict__ csr_src,
                                                 const float* __restrict__ b1,
                                                 unsigned short* __restrict__ h1h, unsigned short* __restrict__ h1l,
                                                 int M) {
    int wv = threadIdx.x >> 6, lane = threadIdx.x & 63;
    int n = blockIdx.x * 4 + wv;
    if (n >= M) return;
    int h = lane >> 4;
    float adv = ad[n * 4 + h];
    int start = rowptr[n], end = rowptr[n + 1];
    float acc0[4] = {0.f, 0.f, 0.f, 0.f}, acc1[4] = {0.f, 0.f, 0.f, 0.f};
    float den0 = 0.f, den1 = 0.f;
    int e = start;
    for (; e + 1 < end; e += 2) {
        int s0 = csr_src[e], s1 = csr_src[e + 1];
        uint2 v0 = *(const uint2*)(xpb + (size_t)s0 * 256 + lane * 4);
        uint2 v1 = *(const uint2*)(xpb + (size_t)s1 * 256 + lane * 4);
        float p0 = __expf(lrelu(as[s0 * 4 + h] + adv));
        float p1 = __expf(lrelu(as[s1 * 4 + h] + adv));
        den0 += p0; den1 += p1;
        acc0[0] += p0 * bflo(v0.x); acc0[1] += p0 * bfhi(v0.x);
        acc0[2] += p0 * bflo(v0.y); acc0[3] += p0 * bfhi(v0.y);
        acc1[0] += p1 * bflo(v1.x); acc1[1] += p1 * bfhi(v1.x);
        acc1[2] += p1 * bflo(v1.y); acc1[3] += p1 * bfhi(v1.y);
    }
    if (e < end) {
        int s0 = csr_src[e];
        uint2 v0 = *(const uint2*)(xpb + (size_t)s0 * 256 + lane * 4);
        float p0 = __expf(lrelu(as[s0 * 4 + h] + adv));
        den0 += p0;
        acc0[0] += p0 * bflo(v0.x); acc0[1] += p0 * bfhi(v0.x);
        acc0[2] += p0 * bflo(v0.y); acc0[3] += p0 * bfhi(v0.y);
    }
    float dinv = 1.f / (den0 + den1 + 1e-16f);
    const float4 bb = *(const float4*)(b1 + lane * 4);
    float o0 = fmaxf((acc0[0] + acc1[0]) * dinv + bb.x, 0.f);
    float o1 = fmaxf((acc0[1] + acc1[1]) * dinv + bb.y, 0.f);
    float o2 = fmaxf((acc0[2] + acc1[2]) * dinv + bb.z, 0.f);
    float o3 = fmaxf((acc0[3] + acc1[3]) * dinv + bb.w, 0.f);
    unsigned short q0 = f2bf(o0), q1 = f2bf(o1), q2 = f2bf(o2), q3 = f2bf(o3);
    uint2 H, L;
    H.x = (unsigned)q0 | ((unsigned)q1 << 16);
    H.y = (unsigned)q2 | ((unsigned)q3 << 16);
    L.x = (unsigned)f2bf(o0 - bf2f(q0)) | ((unsigned)f2bf(o1 - bf2f(q1)) << 16);
    L.y = (unsigned)f2bf(o2 - bf2f(q2)) | ((unsigned)f2bf(o3 - bf2f(q3)) << 16);
    *(uint2*)(h1h + (size_t)n * 256 + lane * 4) = H;
    *(uint2*)(h1l + (size_t)n * 256 + lane * 4) = L;
}

// gather layer 2 (1 head, C=64): 1 wave/node, 4 edge-groups of 16 lanes,
// lane q=lane&15 owns 4 cols (8B). Fused uv = (h2+b2) . Wc halves.
__global__ __launch_bounds__(256) void k_gather2(const unsigned short* __restrict__ xp2b,
                                                 const float* __restrict__ as, const float* __restrict__ ad,
                                                 const int* __restrict__ rowptr, const int* __restrict__ csr_src,
                                                 const float* __restrict__ b2, const float* __restrict__ Wc,
                                                 float* __restrict__ uv, int M) {
    int wv = threadIdx.x >> 6, lane = threadIdx.x & 63;
    int n = blockIdx.x * 4 + wv;
    if (n >= M) return;
    int g = lane >> 4, q = lane & 15;
    float adv = ad[n];
    int start = rowptr[n], end = rowptr[n + 1];
    float acc[4] = {0.f, 0.f, 0.f, 0.f};
    float den = 0.f;
    for (int e = start; e < end; e += 4) {
        int ee = e + g;
        bool ok = ee < end;
        int s = csr_src[ok ? ee : start];
        uint2 v = *(const uint2*)(xp2b + (size_t)s * 64 + q * 4);
        float pw = ok ? __expf(lrelu(as[s] + adv)) : 0.f;
        den += pw;
        acc[0] += pw * bflo(v.x); acc[1] += pw * bfhi(v.x);
        acc[2] += pw * bflo(v.y); acc[3] += pw * bfhi(v.y);
    }
#pragma unroll
    for (int j = 0; j < 4; j++) {
        acc[j] += __shfl_xor(acc[j], 16, 64);
        acc[j] += __shfl_xor(acc[j], 32, 64);
    }
    den += __shfl_xor(den, 16, 64);
    den += __shfl_xor(den, 32, 64);
    float dinv = 1.f / (den + 1e-16f);
    float pr[8] = {0.f, 0.f, 0.f, 0.f, 0.f, 0.f, 0.f, 0.f};
#pragma unroll
    for (int j = 0; j < 4; j++) {
        int c = q * 4 + j;
        float val = acc[j] * dinv + b2[c];
#pragma unroll
        for (int k = 0; k < 4; k++) {
            pr[k]     += val * Wc[c * 4 + k];
            pr[4 + k] += val * Wc[(64 + c) * 4 + k];
        }
    }
#pragma unroll
    for (int off = 1; off <= 8; off <<= 1)
#pragma unroll
        for (int j = 0; j < 8; j++) pr[j] += __shfl_xor(pr[j], off, 64);
    if (lane == 0) {
        float4* o = (float4*)(uv + (size_t)n * 8);
        o[0] = make_float4(pr[0], pr[1], pr[2], pr[3]);
        o[1] = make_float4(pr[4], pr[5], pr[6], pr[7]);
    }
}

__global__ __launch_bounds__(256) void k_classify(const int* __restrict__ ei, const float* __restrict__ uv,
                                                  const float* __restrict__ bc, float* __restrict__ out, int E) {
    int e = blockIdx.x * 256 + threadIdx.x;
    if (e >= E) return;
    int r = ei[e];
    int c = ei[E + e];
    float4 u = *(const float4*)(uv + (size_t)r * 8);
    float4 v = *(const float4*)(uv + (size_t)c * 8 + 4);
    float4 o;
    o.x = u.x + v.x + bc[0];
    o.y = u.y + v.y + bc[1];
    o.z = u.z + v.z + bc[2];
    o.w = u.w + v.w + bc[3];
    *(float4*)(out + (size_t)e * 4) = o;
}

// ---------------------------------------------------------------------------

extern "C" void kernel_launch(void* const* d_in, const int* in_sizes, int n_in,
                              void* d_out, int out_size, void* d_ws, size_t ws_size,
                              hipStream_t stream) {
    const float* x    = (const float*)d_in[0];
    const int*   ei   = (const int*)d_in[1];
    // d_in[2] = w (edge weights) ignored by reference
    const float* W1   = (const float*)d_in[3];
    const float* atS1 = (const float*)d_in[4];
    const float* atD1 = (const float*)d_in[5];
    const float* b1   = (const float*)d_in[6];
    const float* W2   = (const float*)d_in[7];
    const float* atS2 = (const float*)d_in[8];
    const float* atD2 = (const float*)d_in[9];
    const float* b2   = (const float*)d_in[10];
    const float* Wc   = (const float*)d_in[11];
    const float* bc   = (const float*)d_in[12];
    float* out = (float*)d_out;

    const int N = in_sizes[0] / 256;
    const int E = in_sizes[1] / 2;
    const int Etot = E + N;

    char* w = (char*)d_ws;
    size_t off = 0;
    auto alloc = [&](size_t b) { size_t o = off; off = (o + b + 255) & ~(size_t)255; return o; };
    size_t oXH  = alloc((size_t)N * 256 * 2);   // x hi split; later h1h
    size_t oXL  = alloc((size_t)N * 256 * 2);   // x lo split; later h1l
    size_t oXPB = alloc((size_t)N * 256 * 2);   // xp bf16; later xp2b|uv
    size_t oAS1 = alloc((size_t)N * 4 * 4);
    size_t oAD1 = alloc((size_t)N * 4 * 4);
    size_t oDEG = alloc((size_t)N * 4);
    size_t oCUR = alloc((size_t)N * 4);
    size_t oRP  = alloc((size_t)(N + 1) * 4);
    size_t oCSR = alloc((size_t)Etot * 4);
    size_t oW1H = alloc((size_t)256 * 256 * 2);
    size_t oW1L = alloc((size_t)256 * 256 * 2);
    size_t oW2H = alloc((size_t)256 * 64 * 2);
    size_t oW2L = alloc((size_t)256 * 64 * 2);
    (void)ws_size;

    unsigned short* xh   = (unsigned short*)(w + oXH);
    unsigned short* xl   = (unsigned short*)(w + oXL);
    unsigned short* h1h  = (unsigned short*)(w + oXH);   // alias: xh dead after gemm1
    unsigned short* h1l  = (unsigned short*)(w + oXL);
    unsigned short* xpb  = (unsigned short*)(w + oXPB);
    unsigned short* xp2b = (unsigned short*)(w + oXPB);  // alias: xpb dead after gather1
    float* uv  = (float*)(w + oXPB + (size_t)N * 64 * 2 + 256);
    uv = (float*)(((uintptr_t)uv + 255) & ~(uintptr_t)255);
    float* as1 = (float*)(w + oAS1);
    float* ad1 = (float*)(w + oAD1);
    float* as2 = (float*)(w + oAS1);                     // alias: as1 dead after gather1
    float* ad2 = (float*)(w + oAD1);
    int* deg    = (int*)(w + oDEG);
    int* cur    = (int*)(w + oCUR);
    int* rowptr = (int*)(w + oRP);
    int* csr    = (int*)(w + oCSR);
    unsigned short* W1hT = (unsigned short*)(w + oW1H);
    unsigned short* W1lT = (unsigned short*)(w + oW1L);
    unsigned short* W2hT = (unsigned short*)(w + oW2H);
    unsigned short* W2lT = (unsigned short*)(w + oW2L);

    // CSR build
    k_init<<<(N + 255) / 256, 256, 0, stream>>>(deg, cur, N);
    k_hist<<<(E + 255) / 256, 256, 0, stream>>>(ei, deg, E);
    k_scan<<<1, 1024, 0, stream>>>(deg, rowptr, N);
    k_scatter<<<(Etot + 255) / 256, 256, 0, stream>>>(ei, rowptr, cur, csr, E, N);

    // packing
    k_pack_split<<<2048, 256, 0, stream>>>(x, xh, xl, (long)N * 64);
    k_pack_wT<<<(256 * 256 + 255) / 256, 256, 0, stream>>>(W1, W1hT, W1lT, 256, 256);
    k_pack_wT<<<(256 * 64 + 255) / 256, 256, 0, stream>>>(W2, W2hT, W2lT, 256, 64);

    // Layer 1: NF=8, grid.y=2 (wave covers 16 rows x 128 cols), K=256 (8 chunks)
    {
        dim3 g((N + 63) / 64, 2);
        k_mfma_gemmT<8, 8><<<g, 256, 0, stream>>>(xh, xl, W1hT, W1lT, xpb, N, 256, 256);
    }
    k_attn<<<(N * 4 + 255) / 256, 256, 0, stream>>>(xpb, atS1, atD1, as1, ad1, N, 4);
    k_gather1<<<(N + 3) / 4, 256, 0, stream>>>(xpb, as1, ad1, rowptr, csr, b1, h1h, h1l, N);

    // Layer 2: NF=4, grid.y=1, K=256
    {
        dim3 g((N + 63) / 64, 1);
        k_mfma_gemmT<4, 8><<<g, 256, 0, stream>>>(h1h, h1l, W2hT, W2lT, xp2b, N, 64, 256);
    }
    k_attn<<<(N + 255) / 256, 256, 0, stream>>>(xp2b, atS2, atD2, as2, ad2, N, 1);
    k_gather2<<<(N + 3) / 4, 256, 0, stream>>>(xp2b, as2, ad2, rowptr, csr, b2, Wc, uv, N);

    // Edge classifier
    k_classify<<<(E + 255) / 256, 256, 0, stream>>>(ei, uv, bc, out, E);
}

// Round 8
// 391.036 us; speedup vs baseline: 1.2663x; 1.2663x over previous
//
#include <hip/hip_runtime.h>

// ---------------------------------------------------------------------------
// GAT edge classifier, MI355X.
//   CSR build (deg hist -> scan -> scatter)            [int atomics only]
//   pack: x -> (xh, xl) bf16 split; W1,W2 -> transposed bf16 splits
//   GEMM (m97 structure): global_load_lds width=16 staging into LDS,
//     BK=64, 2-barrier single-buffer K-loop, 4 waves, wave=64x64 (4x4 accs),
//     T2 XOR-swizzle (linear LDS dest + inverse-swz global src + swz ds_read).
//     3-term bf16 split (hh + hl + lh). r5-r7 lesson: flat-load register
//     pipelines get re-serialized by the compiler; LDS staging is structural.
//   attn node dots (bf16 reads)
//   gather1: 1 wave/node, 8B/lane, fused p=exp(lrelu(.)), 2-edge ILP
//   GEMM2 -> xp2b; attn2; gather2 (4-edge groups/wave, fused uv=h2@Wc)
//   classify: out[e] = u[row] + v[col] + bc
// ---------------------------------------------------------------------------

#define NEG 0.2f

typedef __attribute__((ext_vector_type(8))) short bf16x8;
typedef __attribute__((ext_vector_type(4))) float f32x4;

__device__ __forceinline__ unsigned short f2bf(float f) {
    unsigned int u = __float_as_uint(f);
    unsigned int r = (u + 0x7FFFu + ((u >> 16) & 1u)) >> 16;   // RNE
    return (unsigned short)r;
}
__device__ __forceinline__ float bf2f(unsigned short h) {
    return __uint_as_float(((unsigned int)h) << 16);
}
__device__ __forceinline__ float bflo(unsigned int u) { return __uint_as_float(u << 16); }
__device__ __forceinline__ float bfhi(unsigned int u) { return __uint_as_float(u & 0xFFFF0000u); }
__device__ __forceinline__ float lrelu(float x) { return x > 0.f ? x : NEG * x; }

// async global->LDS, 16 bytes per lane. Dest is wave-uniform base + lane*16.
__device__ __forceinline__ void async16(const void* g, void* l) {
    __builtin_amdgcn_global_load_lds(
        (const __attribute__((address_space(1))) unsigned int*)g,
        (__attribute__((address_space(3))) unsigned int*)l, 16, 0, 0);
}

// ------------------------------- CSR build --------------------------------

__global__ __launch_bounds__(256) void k_init(int* deg, int* cur, int n) {
    int i = blockIdx.x * 256 + threadIdx.x;
    if (i < n) { deg[i] = 1; cur[i] = 0; }  // deg starts at 1 for self-loop
}

__global__ __launch_bounds__(256) void k_hist(const int* __restrict__ ei, int* deg, int E) {
    int e = blockIdx.x * 256 + threadIdx.x;
    if (e < E) atomicAdd(&deg[ei[E + e]], 1);   // dst = ei[1][e]
}

__global__ __launch_bounds__(1024) void k_scan(const int* __restrict__ deg, int* __restrict__ rowptr, int n) {
    __shared__ int sums[1024];
    int t = threadIdx.x;
    int chunk = (n + 1023) >> 10;
    int lo = t * chunk, hi = min(lo + chunk, n);
    int s = 0;
    for (int i = lo; i < hi; i++) s += deg[i];
    sums[t] = s;
    __syncthreads();
    for (int off = 1; off < 1024; off <<= 1) {
        int v = (t >= off) ? sums[t - off] : 0;
        __syncthreads();
        sums[t] += v;
        __syncthreads();
    }
    int run = sums[t] - s;  // exclusive prefix at lo
    for (int i = lo; i < hi; i++) { rowptr[i] = run; run += deg[i]; }
    if (t == 1023) rowptr[n] = sums[1023];
}

__global__ __launch_bounds__(256) void k_scatter(const int* __restrict__ ei, const int* __restrict__ rowptr,
                                                 int* cur, int* csr_src, int E, int N) {
    int e = blockIdx.x * 256 + threadIdx.x;
    if (e < E) {
        int d = ei[E + e];
        int pos = rowptr[d] + atomicAdd(&cur[d], 1);
        csr_src[pos] = ei[e];
    } else if (e < E + N) {
        int i = e - E;  // self loop
        int pos = rowptr[i] + atomicAdd(&cur[i], 1);
        csr_src[pos] = i;
    }
}

// ------------------------------- packing ----------------------------------

__global__ __launch_bounds__(256) void k_pack_split(const float* __restrict__ src,
                                                    unsigned short* __restrict__ hi,
                                                    unsigned short* __restrict__ lo, long n4) {
    long i = (long)blockIdx.x * 256 + threadIdx.x;
    long stride = (long)gridDim.x * 256;
    for (; i < n4; i += stride) {
        float4 v = ((const float4*)src)[i];
        unsigned short h0 = f2bf(v.x), h1 = f2bf(v.y), h2 = f2bf(v.z), h3 = f2bf(v.w);
        ushort4 H = make_ushort4(h0, h1, h2, h3);
        ushort4 L = make_ushort4(f2bf(v.x - bf2f(h0)), f2bf(v.y - bf2f(h1)),
                                 f2bf(v.z - bf2f(h2)), f2bf(v.w - bf2f(h3)));
        ((ushort4*)hi)[i] = H;
        ((ushort4*)lo)[i] = L;
    }
}

// W [K,N] fp32 -> WT hi/lo bf16 [N,K]
__global__ __launch_bounds__(256) void k_pack_wT(const float* __restrict__ W,
                                                 unsigned short* __restrict__ hiT,
                                                 unsigned short* __restrict__ loT, int K, int N) {
    int t = blockIdx.x * 256 + threadIdx.x;
    if (t >= K * N) return;
    int n = t / K, k = t - n * K;
    float v = W[(size_t)k * N + n];
    unsigned short h = f2bf(v);
    hiT[t] = h;
    loT[t] = f2bf(v - bf2f(h));
}

// ------------------------------- MFMA GEMM (LDS, m97 structure) -----------
// C[M,N] = A[M,K] @ B[K,N]; A hi/lo bf16 row-major, B hi/lo bf16 [N,K].
// Block = 4 waves; BM=WGM*64, BN=WGN*64; BK=64 (2 MFMA k-steps).
// LDS layout per array: [rows][128B] linear, content XOR-swizzled:
//   LDS[row*128 + (cb ^ ((row&7)<<4))] = src[row][cb]   (cb = k-byte, 16B grains)
// Staged by global_load_lds: lane l of seg s covers row=s*8+(l>>3),
//   grain (l&7): src col byte = ((l&7)^(l>>3))<<4  (inverse-swizzled source).
// ds_read_b128 applies the same XOR -> 16 lanes spread over 32 banks (2-way).
template<int WGM, int WGN>
__global__ __launch_bounds__(256, 2) void k_gemm_lds(const unsigned short* __restrict__ Ah,
                                                     const unsigned short* __restrict__ Al,
                                                     const unsigned short* __restrict__ BhT,
                                                     const unsigned short* __restrict__ BlT,
                                                     unsigned short* __restrict__ Cb, int M, int N, int K) {
    constexpr int BM = WGM * 64, BN = WGN * 64;
    __shared__ char lds[(BM + BN) * 256];          // Ah|Al|Bh|Bl, each rows*128
    char* LAh = lds;
    char* LAl = lds + BM * 128;
    char* LBh = lds + 2 * BM * 128;
    char* LBl = lds + 2 * BM * 128 + BN * 128;

    const int t = threadIdx.x, wv = t >> 6, l = t & 63;
    const int r = l & 15, hk = l >> 4;
    const int m0 = blockIdx.x * BM;
    const int n0 = blockIdx.y * BN;
    const int wr = wv / WGN, wc = wv % WGN;
    const int wrow0 = wr * 64, wcol0 = wc * 64;

    f32x4 acc[4][4];
#pragma unroll
    for (int i = 0; i < 4; i++)
#pragma unroll
        for (int j = 0; j < 4; j++) acc[i][j] = f32x4{0, 0, 0, 0};

    const int lrow8 = l >> 3;                       // 0..7
    const int cbs = ((l & 7) ^ lrow8) << 4;         // inverse-swizzled src col byte
    const size_t K2 = (size_t)K * 2;
    const int NCH = K >> 6;

    for (int c = 0; c < NCH; ++c) {
        const int kk2 = c * 128;
        // ---- stage chunk c (async, drains at the barrier) ----
        {
            const int SA = BM / 8;
            for (int i = wv; i < SA; i += 4) {
                int row = i * 8 + lrow8;
                size_t go = (size_t)(m0 + row) * K2 + kk2 + cbs;
                async16((const char*)Ah + go, LAh + i * 1024);
                async16((const char*)Al + go, LAl + i * 1024);
            }
            const int SB = BN / 8;
            for (int i = wv; i < SB; i += 4) {
                int row = i * 8 + lrow8;
                size_t go = (size_t)(n0 + row) * K2 + kk2 + cbs;
                async16((const char*)BhT + go, LBh + i * 1024);
                async16((const char*)BlT + go, LBl + i * 1024);
            }
        }
        __syncthreads();   // compiler emits vmcnt(0) drain: LDS tile ready
        // ---- compute chunk c ----
#pragma unroll
        for (int ks = 0; ks < 2; ++ks) {
            const int cb = ks * 64 + hk * 16;
            bf16x8 a_h[4], a_l[4], b_h[4], b_l[4];
#pragma unroll
            for (int fm = 0; fm < 4; ++fm) {
                int row = wrow0 + fm * 16 + r;
                int ad = row * 128 + (cb ^ ((row & 7) << 4));
                a_h[fm] = *(const bf16x8*)(LAh + ad);
                a_l[fm] = *(const bf16x8*)(LAl + ad);
            }
#pragma unroll
            for (int fn = 0; fn < 4; ++fn) {
                int row = wcol0 + fn * 16 + r;
                int ad = row * 128 + (cb ^ ((row & 7) << 4));
                b_h[fn] = *(const bf16x8*)(LBh + ad);
                b_l[fn] = *(const bf16x8*)(LBl + ad);
            }
#pragma unroll
            for (int fm = 0; fm < 4; ++fm)
#pragma unroll
                for (int fn = 0; fn < 4; ++fn) {
                    acc[fm][fn] = __builtin_amdgcn_mfma_f32_16x16x32_bf16(a_h[fm], b_h[fn], acc[fm][fn], 0, 0, 0);
                    acc[fm][fn] = __builtin_amdgcn_mfma_f32_16x16x32_bf16(a_h[fm], b_l[fn], acc[fm][fn], 0, 0, 0);
                    acc[fm][fn] = __builtin_amdgcn_mfma_f32_16x16x32_bf16(a_l[fm], b_h[fn], acc[fm][fn], 0, 0, 0);
                }
        }
        if (c + 1 < NCH) __syncthreads();   // all reads done before restage
    }

    // ---- epilogue: C/D frag (col=lane&15, row=(lane>>4)*4+j) -> bf16 ----
#pragma unroll
    for (int fm = 0; fm < 4; ++fm)
#pragma unroll
        for (int fn = 0; fn < 4; ++fn)
#pragma unroll
            for (int j = 0; j < 4; ++j) {
                int m = m0 + wrow0 + fm * 16 + hk * 4 + j;
                if (m < M) Cb[(size_t)m * N + n0 + wcol0 + fn * 16 + r] = f2bf(acc[fm][fn][j]);
            }
}

// ------------------------------- attention --------------------------------

// a_src/a_dst[n,h] from bf16 xpb; H heads of C=64 channels, thread=(n,h)
__global__ __launch_bounds__(256) void k_attn(const unsigned short* __restrict__ xpb,
                                              const float* __restrict__ att_s,
                                              const float* __restrict__ att_d,
                                              float* __restrict__ as, float* __restrict__ ad,
                                              int M, int H) {
    int idx = blockIdx.x * 256 + threadIdx.x;
    if (idx >= M * H) return;
    int n = idx / H, h = idx - n * H;
    const uint4* row = (const uint4*)(xpb + (size_t)n * (64 * H) + h * 64);
    const float* fs = att_s + h * 64;
    const float* fd = att_d + h * 64;
    float s = 0.f, d = 0.f;
#pragma unroll
    for (int j = 0; j < 8; j++) {
        uint4 v = row[j];
        unsigned int uu[4] = {v.x, v.y, v.z, v.w};
#pragma unroll
        for (int q = 0; q < 4; q++) {
            float lo = bflo(uu[q]);
            float hi = bfhi(uu[q]);
            int c = j * 8 + q * 2;
            s += lo * fs[c] + hi * fs[c + 1];
            d += lo * fd[c] + hi * fd[c + 1];
        }
    }
    as[idx] = s; ad[idx] = d;
}

// gather layer 1: 1 wave/node, lane owns 4 cols (8B), head h=lane>>4.
__global__ __launch_bounds__(256) void k_gather1(const unsigned short* __restrict__ xpb,
                                                 const float* __restrict__ as, const float* __restrict__ ad,
                                                 const int* __restrict__ rowptr, const int* __restrict__ csr_src,
                                                 const float* __restrict__ b1,
                                                 unsigned short* __restrict__ h1h, unsigned short* __restrict__ h1l,
                                                 int M) {
    int wv = threadIdx.x >> 6, lane = threadIdx.x & 63;
    int n = blockIdx.x * 4 + wv;
    if (n >= M) return;
    int h = lane >> 4;
    float adv = ad[n * 4 + h];
    int start = rowptr[n], end = rowptr[n + 1];
    float acc0[4] = {0.f, 0.f, 0.f, 0.f}, acc1[4] = {0.f, 0.f, 0.f, 0.f};
    float den0 = 0.f, den1 = 0.f;
    int e = start;
    for (; e + 1 < end; e += 2) {
        int s0 = csr_src[e], s1 = csr_src[e + 1];
        uint2 v0 = *(const uint2*)(xpb + (size_t)s0 * 256 + lane * 4);
        uint2 v1 = *(const uint2*)(xpb + (size_t)s1 * 256 + lane * 4);
        float p0 = __expf(lrelu(as[s0 * 4 + h] + adv));
        float p1 = __expf(lrelu(as[s1 * 4 + h] + adv));
        den0 += p0; den1 += p1;
        acc0[0] += p0 * bflo(v0.x); acc0[1] += p0 * bfhi(v0.x);
        acc0[2] += p0 * bflo(v0.y); acc0[3] += p0 * bfhi(v0.y);
        acc1[0] += p1 * bflo(v1.x); acc1[1] += p1 * bfhi(v1.x);
        acc1[2] += p1 * bflo(v1.y); acc1[3] += p1 * bfhi(v1.y);
    }
    if (e < end) {
        int s0 = csr_src[e];
        uint2 v0 = *(const uint2*)(xpb + (size_t)s0 * 256 + lane * 4);
        float p0 = __expf(lrelu(as[s0 * 4 + h] + adv));
        den0 += p0;
        acc0[0] += p0 * bflo(v0.x); acc0[1] += p0 * bfhi(v0.x);
        acc0[2] += p0 * bflo(v0.y); acc0[3] += p0 * bfhi(v0.y);
    }
    float dinv = 1.f / (den0 + den1 + 1e-16f);
    const float4 bb = *(const float4*)(b1 + lane * 4);
    float o0 = fmaxf((acc0[0] + acc1[0]) * dinv + bb.x, 0.f);
    float o1 = fmaxf((acc0[1] + acc1[1]) * dinv + bb.y, 0.f);
    float o2 = fmaxf((acc0[2] + acc1[2]) * dinv + bb.z, 0.f);
    float o3 = fmaxf((acc0[3] + acc1[3]) * dinv + bb.w, 0.f);
    unsigned short q0 = f2bf(o0), q1 = f2bf(o1), q2 = f2bf(o2), q3 = f2bf(o3);
    uint2 H, L;
    H.x = (unsigned)q0 | ((unsigned)q1 << 16);
    H.y = (unsigned)q2 | ((unsigned)q3 << 16);
    L.x = (unsigned)f2bf(o0 - bf2f(q0)) | ((unsigned)f2bf(o1 - bf2f(q1)) << 16);
    L.y = (unsigned)f2bf(o2 - bf2f(q2)) | ((unsigned)f2bf(o3 - bf2f(q3)) << 16);
    *(uint2*)(h1h + (size_t)n * 256 + lane * 4) = H;
    *(uint2*)(h1l + (size_t)n * 256 + lane * 4) = L;
}

// gather layer 2 (1 head, C=64): 1 wave/node, 4 edge-groups of 16 lanes.
__global__ __launch_bounds__(256) void k_gather2(const unsigned short* __restrict__ xp2b,
                                                 const float* __restrict__ as, const float* __restrict__ ad,
                                                 const int* __restrict__ rowptr, const int* __restrict__ csr_src,
                                                 const float* __restrict__ b2, const float* __restrict__ Wc,
                                                 float* __restrict__ uv, int M) {
    int wv = threadIdx.x >> 6, lane = threadIdx.x & 63;
    int n = blockIdx.x * 4 + wv;
    if (n >= M) return;
    int g = lane >> 4, q = lane & 15;
    float adv = ad[n];
    int start = rowptr[n], end = rowptr[n + 1];
    float acc[4] = {0.f, 0.f, 0.f, 0.f};
    float den = 0.f;
    for (int e = start; e < end; e += 4) {
        int ee = e + g;
        bool ok = ee < end;
        int s = csr_src[ok ? ee : start];
        uint2 v = *(const uint2*)(xp2b + (size_t)s * 64 + q * 4);
        float pw = ok ? __expf(lrelu(as[s] + adv)) : 0.f;
        den += pw;
        acc[0] += pw * bflo(v.x); acc[1] += pw * bfhi(v.x);
        acc[2] += pw * bflo(v.y); acc[3] += pw * bfhi(v.y);
    }
#pragma unroll
    for (int j = 0; j < 4; j++) {
        acc[j] += __shfl_xor(acc[j], 16, 64);
        acc[j] += __shfl_xor(acc[j], 32, 64);
    }
    den += __shfl_xor(den, 16, 64);
    den += __shfl_xor(den, 32, 64);
    float dinv = 1.f / (den + 1e-16f);
    float pr[8] = {0.f, 0.f, 0.f, 0.f, 0.f, 0.f, 0.f, 0.f};
#pragma unroll
    for (int j = 0; j < 4; j++) {
        int c = q * 4 + j;
        float val = acc[j] * dinv + b2[c];
#pragma unroll
        for (int k = 0; k < 4; k++) {
            pr[k]     += val * Wc[c * 4 + k];
            pr[4 + k] += val * Wc[(64 + c) * 4 + k];
        }
    }
#pragma unroll
    for (int off = 1; off <= 8; off <<= 1)
#pragma unroll
        for (int j = 0; j < 8; j++) pr[j] += __shfl_xor(pr[j], off, 64);
    if (lane == 0) {
        float4* o = (float4*)(uv + (size_t)n * 8);
        o[0] = make_float4(pr[0], pr[1], pr[2], pr[3]);
        o[1] = make_float4(pr[4], pr[5], pr[6], pr[7]);
    }
}

__global__ __launch_bounds__(256) void k_classify(const int* __restrict__ ei, const float* __restrict__ uv,
                                                  const float* __restrict__ bc, float* __restrict__ out, int E) {
    int e = blockIdx.x * 256 + threadIdx.x;
    if (e >= E) return;
    int r = ei[e];
    int c = ei[E + e];
    float4 u = *(const float4*)(uv + (size_t)r * 8);
    float4 v = *(const float4*)(uv + (size_t)c * 8 + 4);
    float4 o;
    o.x = u.x + v.x + bc[0];
    o.y = u.y + v.y + bc[1];
    o.z = u.z + v.z + bc[2];
    o.w = u.w + v.w + bc[3];
    *(float4*)(out + (size_t)e * 4) = o;
}

// ---------------------------------------------------------------------------

extern "C" void kernel_launch(void* const* d_in, const int* in_sizes, int n_in,
                              void* d_out, int out_size, void* d_ws, size_t ws_size,
                              hipStream_t stream) {
    const float* x    = (const float*)d_in[0];
    const int*   ei   = (const int*)d_in[1];
    // d_in[2] = w (edge weights) ignored by reference
    const float* W1   = (const float*)d_in[3];
    const float* atS1 = (const float*)d_in[4];
    const float* atD1 = (const float*)d_in[5];
    const float* b1   = (const float*)d_in[6];
    const float* W2   = (const float*)d_in[7];
    const float* atS2 = (const float*)d_in[8];
    const float* atD2 = (const float*)d_in[9];
    const float* b2   = (const float*)d_in[10];
    const float* Wc   = (const float*)d_in[11];
    const float* bc   = (const float*)d_in[12];
    float* out = (float*)d_out;

    const int Nn = in_sizes[0] / 256;   // nodes
    const int E = in_sizes[1] / 2;
    const int Etot = E + Nn;

    char* w = (char*)d_ws;
    size_t off = 0;
    auto alloc = [&](size_t b) { size_t o = off; off = (o + b + 255) & ~(size_t)255; return o; };
    size_t oXH  = alloc((size_t)Nn * 256 * 2);   // x hi split; later h1h
    size_t oXL  = alloc((size_t)Nn * 256 * 2);   // x lo split; later h1l
    size_t oXPB = alloc((size_t)Nn * 256 * 2);   // xp bf16; later xp2b|uv
    size_t oAS1 = alloc((size_t)Nn * 4 * 4);
    size_t oAD1 = alloc((size_t)Nn * 4 * 4);
    size_t oDEG = alloc((size_t)Nn * 4);
    size_t oCUR = alloc((size_t)Nn * 4);
    size_t oRP  = alloc((size_t)(Nn + 1) * 4);
    size_t oCSR = alloc((size_t)Etot * 4);
    size_t oW1H = alloc((size_t)256 * 256 * 2);
    size_t oW1L = alloc((size_t)256 * 256 * 2);
    size_t oW2H = alloc((size_t)256 * 64 * 2);
    size_t oW2L = alloc((size_t)256 * 64 * 2);
    (void)ws_size;

    unsigned short* xh   = (unsigned short*)(w + oXH);
    unsigned short* xl   = (unsigned short*)(w + oXL);
    unsigned short* h1h  = (unsigned short*)(w + oXH);   // alias: xh dead after gemm1
    unsigned short* h1l  = (unsigned short*)(w + oXL);
    unsigned short* xpb  = (unsigned short*)(w + oXPB);
    unsigned short* xp2b = (unsigned short*)(w + oXPB);  // alias: xpb dead after gather1
    float* uv  = (float*)(w + oXPB + (size_t)Nn * 64 * 2 + 256);
    uv = (float*)(((uintptr_t)uv + 255) & ~(uintptr_t)255);
    float* as1 = (float*)(w + oAS1);
    float* ad1 = (float*)(w + oAD1);
    float* as2 = (float*)(w + oAS1);                     // alias: as1 dead after gather1
    float* ad2 = (float*)(w + oAD1);
    int* deg    = (int*)(w + oDEG);
    int* cur    = (int*)(w + oCUR);
    int* rowptr = (int*)(w + oRP);
    int* csr    = (int*)(w + oCSR);
    unsigned short* W1hT = (unsigned short*)(w + oW1H);
    unsigned short* W1lT = (unsigned short*)(w + oW1L);
    unsigned short* W2hT = (unsigned short*)(w + oW2H);
    unsigned short* W2lT = (unsigned short*)(w + oW2L);

    // CSR build
    k_init<<<(Nn + 255) / 256, 256, 0, stream>>>(deg, cur, Nn);
    k_hist<<<(E + 255) / 256, 256, 0, stream>>>(ei, deg, E);
    k_scan<<<1, 1024, 0, stream>>>(deg, rowptr, Nn);
    k_scatter<<<(Etot + 255) / 256, 256, 0, stream>>>(ei, rowptr, cur, csr, E, Nn);

    // packing
    k_pack_split<<<2048, 256, 0, stream>>>(x, xh, xl, (long)Nn * 64);
    k_pack_wT<<<(256 * 256 + 255) / 256, 256, 0, stream>>>(W1, W1hT, W1lT, 256, 256);
    k_pack_wT<<<(256 * 64 + 255) / 256, 256, 0, stream>>>(W2, W2hT, W2lT, 256, 64);

    // Layer 1: 128x128 tile (WGM=2, WGN=2), grid.y = 256/128 = 2
    {
        dim3 g((Nn + 127) / 128, 2);
        k_gemm_lds<2, 2><<<g, 256, 0, stream>>>(xh, xl, W1hT, W1lT, xpb, Nn, 256, 256);
    }
    k_attn<<<(Nn * 4 + 255) / 256, 256, 0, stream>>>(xpb, atS1, atD1, as1, ad1, Nn, 4);
    k_gather1<<<(Nn + 3) / 4, 256, 0, stream>>>(xpb, as1, ad1, rowptr, csr, b1, h1h, h1l, Nn);

    // Layer 2: 256x64 tile (WGM=4, WGN=1), grid.y = 1
    {
        dim3 g((Nn + 255) / 256, 1);
        k_gemm_lds<4, 1><<<g, 256, 0, stream>>>(h1h, h1l, W2hT, W2lT, xp2b, Nn, 64, 256);
    }
    k_attn<<<(Nn + 255) / 256, 256, 0, stream>>>(xp2b, atS2, atD2, as2, ad2, Nn, 1);
    k_gather2<<<(Nn + 3) / 4, 256, 0, stream>>>(xp2b, as2, ad2, rowptr, csr, b2, Wc, uv, Nn);

    // Edge classifier
    k_classify<<<(E + 255) / 256, 256, 0, stream>>>(ei, uv, bc, out, E);
}

// Round 9
// 315.912 us; speedup vs baseline: 1.5675x; 1.2378x over previous
//
#include <hip/hip_runtime.h>

// ---------------------------------------------------------------------------
// GAT edge classifier, MI355X.
//   CSR build: deg hist -> 3-phase parallel scan (r8: single-block scan was
//     77us on one CU) -> scatter                        [int atomics only]
//   pack: x -> (xh, xl) bf16 split; W1,W2 -> transposed bf16 splits
//   GEMM (m97 structure): global_load_lds width=16 staging into LDS,
//     BK=64, 2-barrier single-buffer K-loop, 4 waves, wave=64x64 (4x4 accs),
//     T2 XOR-swizzle (linear LDS dest + inverse-swz global src + swz ds_read).
//   attn node dots (bf16 reads)
//   gather1: 1 wave/node, 8B/lane, fused p=exp(lrelu(.)), 2-edge ILP
//   GEMM2 -> xp2b; attn2; gather2 (4-edge groups/wave, fused uv=h2@Wc)
//   classify: out[e] = u[row] + v[col] + bc
// ---------------------------------------------------------------------------

#define NEG 0.2f

typedef __attribute__((ext_vector_type(8))) short bf16x8;
typedef __attribute__((ext_vector_type(4))) float f32x4;

__device__ __forceinline__ unsigned short f2bf(float f) {
    unsigned int u = __float_as_uint(f);
    unsigned int r = (u + 0x7FFFu + ((u >> 16) & 1u)) >> 16;   // RNE
    return (unsigned short)r;
}
__device__ __forceinline__ float bf2f(unsigned short h) {
    return __uint_as_float(((unsigned int)h) << 16);
}
__device__ __forceinline__ float bflo(unsigned int u) { return __uint_as_float(u << 16); }
__device__ __forceinline__ float bfhi(unsigned int u) { return __uint_as_float(u & 0xFFFF0000u); }
__device__ __forceinline__ float lrelu(float x) { return x > 0.f ? x : NEG * x; }

// async global->LDS, 16 bytes per lane. Dest is wave-uniform base + lane*16.
__device__ __forceinline__ void async16(const void* g, void* l) {
    __builtin_amdgcn_global_load_lds(
        (const __attribute__((address_space(1))) unsigned int*)g,
        (__attribute__((address_space(3))) unsigned int*)l, 16, 0, 0);
}

// ------------------------------- CSR build --------------------------------

__global__ __launch_bounds__(256) void k_init(int* deg, int* cur, int n) {
    int i = blockIdx.x * 256 + threadIdx.x;
    if (i < n) { deg[i] = 1; cur[i] = 0; }  // deg starts at 1 for self-loop
}

__global__ __launch_bounds__(256) void k_hist(const int* __restrict__ ei, int* deg, int E) {
    int e = blockIdx.x * 256 + threadIdx.x;
    if (e < E) atomicAdd(&deg[ei[E + e]], 1);   // dst = ei[1][e]
}

// ---- 3-phase parallel scan (replaces 77us single-block k_scan) ----
__global__ __launch_bounds__(256) void k_bsum(const int* __restrict__ deg, int* __restrict__ bsum, int n) {
    int i = blockIdx.x * 256 + threadIdx.x;
    int v = (i < n) ? deg[i] : 0;
#pragma unroll
    for (int off = 1; off < 64; off <<= 1) v += __shfl_xor(v, off, 64);
    __shared__ int ws[4];
    int wv = threadIdx.x >> 6, l = threadIdx.x & 63;
    if (l == 0) ws[wv] = v;
    __syncthreads();
    if (threadIdx.x == 0) bsum[blockIdx.x] = ws[0] + ws[1] + ws[2] + ws[3];
}

// exclusive scan of bsum[0..nb), nb <= 256; also writes rowptr[n] = total
__global__ __launch_bounds__(256) void k_bscan(const int* __restrict__ bsum, int* __restrict__ boff,
                                               int* __restrict__ rowptr, int nb, int n) {
    __shared__ int s[256];
    int t = threadIdx.x;
    int v = (t < nb) ? bsum[t] : 0;
    s[t] = v;
    __syncthreads();
    for (int off = 1; off < 256; off <<= 1) {
        int u = (t >= off) ? s[t - off] : 0;
        __syncthreads();
        s[t] += u;
        __syncthreads();
    }
    if (t < nb) boff[t] = s[t] - v;
    if (t == nb - 1) rowptr[n] = s[t];
}

__global__ __launch_bounds__(256) void k_rowptr(const int* __restrict__ deg, const int* __restrict__ boff,
                                                int* __restrict__ rowptr, int n) {
    __shared__ int s[256];
    int i = blockIdx.x * 256 + threadIdx.x;
    int t = threadIdx.x;
    int v = (i < n) ? deg[i] : 0;
    s[t] = v;
    __syncthreads();
    for (int off = 1; off < 256; off <<= 1) {
        int u = (t >= off) ? s[t - off] : 0;
        __syncthreads();
        s[t] += u;
        __syncthreads();
    }
    if (i < n) rowptr[i] = boff[blockIdx.x] + s[t] - v;
}

__global__ __launch_bounds__(256) void k_scatter(const int* __restrict__ ei, const int* __restrict__ rowptr,
                                                 int* cur, int* csr_src, int E, int N) {
    int e = blockIdx.x * 256 + threadIdx.x;
    if (e < E) {
        int d = ei[E + e];
        int pos = rowptr[d] + atomicAdd(&cur[d], 1);
        csr_src[pos] = ei[e];
    } else if (e < E + N) {
        int i = e - E;  // self loop
        int pos = rowptr[i] + atomicAdd(&cur[i], 1);
        csr_src[pos] = i;
    }
}

// ------------------------------- packing ----------------------------------

__global__ __launch_bounds__(256) void k_pack_split(const float* __restrict__ src,
                                                    unsigned short* __restrict__ hi,
                                                    unsigned short* __restrict__ lo, long n4) {
    long i = (long)blockIdx.x * 256 + threadIdx.x;
    long stride = (long)gridDim.x * 256;
    for (; i < n4; i += stride) {
        float4 v = ((const float4*)src)[i];
        unsigned short h0 = f2bf(v.x), h1 = f2bf(v.y), h2 = f2bf(v.z), h3 = f2bf(v.w);
        ushort4 H = make_ushort4(h0, h1, h2, h3);
        ushort4 L = make_ushort4(f2bf(v.x - bf2f(h0)), f2bf(v.y - bf2f(h1)),
                                 f2bf(v.z - bf2f(h2)), f2bf(v.w - bf2f(h3)));
        ((ushort4*)hi)[i] = H;
        ((ushort4*)lo)[i] = L;
    }
}

// W [K,N] fp32 -> WT hi/lo bf16 [N,K]
__global__ __launch_bounds__(256) void k_pack_wT(const float* __restrict__ W,
                                                 unsigned short* __restrict__ hiT,
                                                 unsigned short* __restrict__ loT, int K, int N) {
    int t = blockIdx.x * 256 + threadIdx.x;
    if (t >= K * N) return;
    int n = t / K, k = t - n * K;
    float v = W[(size_t)k * N + n];
    unsigned short h = f2bf(v);
    hiT[t] = h;
    loT[t] = f2bf(v - bf2f(h));
}

// ------------------------------- MFMA GEMM (LDS, m97 structure) -----------
// See r7/r8 notes: global_load_lds staging, BK=64, XOR-swizzle both sides.
template<int WGM, int WGN>
__global__ __launch_bounds__(256, 2) void k_gemm_lds(const unsigned short* __restrict__ Ah,
                                                     const unsigned short* __restrict__ Al,
                                                     const unsigned short* __restrict__ BhT,
                                                     const unsigned short* __restrict__ BlT,
                                                     unsigned short* __restrict__ Cb, int M, int N, int K) {
    constexpr int BM = WGM * 64, BN = WGN * 64;
    __shared__ char lds[(BM + BN) * 256];          // Ah|Al|Bh|Bl, each rows*128
    char* LAh = lds;
    char* LAl = lds + BM * 128;
    char* LBh = lds + 2 * BM * 128;
    char* LBl = lds + 2 * BM * 128 + BN * 128;

    const int t = threadIdx.x, wv = t >> 6, l = t & 63;
    const int r = l & 15, hk = l >> 4;
    const int m0 = blockIdx.x * BM;
    const int n0 = blockIdx.y * BN;
    const int wr = wv / WGN, wc = wv % WGN;
    const int wrow0 = wr * 64, wcol0 = wc * 64;

    f32x4 acc[4][4];
#pragma unroll
    for (int i = 0; i < 4; i++)
#pragma unroll
        for (int j = 0; j < 4; j++) acc[i][j] = f32x4{0, 0, 0, 0};

    const int lrow8 = l >> 3;                       // 0..7
    const int cbs = ((l & 7) ^ lrow8) << 4;         // inverse-swizzled src col byte
    const size_t K2 = (size_t)K * 2;
    const int NCH = K >> 6;

    for (int c = 0; c < NCH; ++c) {
        const int kk2 = c * 128;
        {
            const int SA = BM / 8;
            for (int i = wv; i < SA; i += 4) {
                int row = i * 8 + lrow8;
                size_t go = (size_t)(m0 + row) * K2 + kk2 + cbs;
                async16((const char*)Ah + go, LAh + i * 1024);
                async16((const char*)Al + go, LAl + i * 1024);
            }
            const int SB = BN / 8;
            for (int i = wv; i < SB; i += 4) {
                int row = i * 8 + lrow8;
                size_t go = (size_t)(n0 + row) * K2 + kk2 + cbs;
                async16((const char*)BhT + go, LBh + i * 1024);
                async16((const char*)BlT + go, LBl + i * 1024);
            }
        }
        __syncthreads();
#pragma unroll
        for (int ks = 0; ks < 2; ++ks) {
            const int cb = ks * 64 + hk * 16;
            bf16x8 a_h[4], a_l[4], b_h[4], b_l[4];
#pragma unroll
            for (int fm = 0; fm < 4; ++fm) {
                int row = wrow0 + fm * 16 + r;
                int ad = row * 128 + (cb ^ ((row & 7) << 4));
                a_h[fm] = *(const bf16x8*)(LAh + ad);
                a_l[fm] = *(const bf16x8*)(LAl + ad);
            }
#pragma unroll
            for (int fn = 0; fn < 4; ++fn) {
                int row = wcol0 + fn * 16 + r;
                int ad = row * 128 + (cb ^ ((row & 7) << 4));
                b_h[fn] = *(const bf16x8*)(LBh + ad);
                b_l[fn] = *(const bf16x8*)(LBl + ad);
            }
#pragma unroll
            for (int fm = 0; fm < 4; ++fm)
#pragma unroll
                for (int fn = 0; fn < 4; ++fn) {
                    acc[fm][fn] = __builtin_amdgcn_mfma_f32_16x16x32_bf16(a_h[fm], b_h[fn], acc[fm][fn], 0, 0, 0);
                    acc[fm][fn] = __builtin_amdgcn_mfma_f32_16x16x32_bf16(a_h[fm], b_l[fn], acc[fm][fn], 0, 0, 0);
                    acc[fm][fn] = __builtin_amdgcn_mfma_f32_16x16x32_bf16(a_l[fm], b_h[fn], acc[fm][fn], 0, 0, 0);
                }
        }
        if (c + 1 < NCH) __syncthreads();
    }

#pragma unroll
    for (int fm = 0; fm < 4; ++fm)
#pragma unroll
        for (int fn = 0; fn < 4; ++fn)
#pragma unroll
            for (int j = 0; j < 4; ++j) {
                int m = m0 + wrow0 + fm * 16 + hk * 4 + j;
                if (m < M) Cb[(size_t)m * N + n0 + wcol0 + fn * 16 + r] = f2bf(acc[fm][fn][j]);
            }
}

// ------------------------------- attention --------------------------------

__global__ __launch_bounds__(256) void k_attn(const unsigned short* __restrict__ xpb,
                                              const float* __restrict__ att_s,
                                              const float* __restrict__ att_d,
                                              float* __restrict__ as, float* __restrict__ ad,
                                              int M, int H) {
    int idx = blockIdx.x * 256 + threadIdx.x;
    if (idx >= M * H) return;
    int n = idx / H, h = idx - n * H;
    const uint4* row = (const uint4*)(xpb + (size_t)n * (64 * H) + h * 64);
    const float* fs = att_s + h * 64;
    const float* fd = att_d + h * 64;
    float s = 0.f, d = 0.f;
#pragma unroll
    for (int j = 0; j < 8; j++) {
        uint4 v = row[j];
        unsigned int uu[4] = {v.x, v.y, v.z, v.w};
#pragma unroll
        for (int q = 0; q < 4; q++) {
            float lo = bflo(uu[q]);
            float hi = bfhi(uu[q]);
            int c = j * 8 + q * 2;
            s += lo * fs[c] + hi * fs[c + 1];
            d += lo * fd[c] + hi * fd[c + 1];
        }
    }
    as[idx] = s; ad[idx] = d;
}

// gather layer 1: 1 wave/node, lane owns 4 cols (8B), head h=lane>>4.
__global__ __launch_bounds__(256) void k_gather1(const unsigned short* __restrict__ xpb,
                                                 const float* __restrict__ as, const float* __restrict__ ad,
                                                 const int* __restrict__ rowptr, const int* __restrict__ csr_src,
                                                 const float* __restrict__ b1,
                                                 unsigned short* __restrict__ h1h, unsigned short* __restrict__ h1l,
                                                 int M) {
    int wv = threadIdx.x >> 6, lane = threadIdx.x & 63;
    int n = blockIdx.x * 4 + wv;
    if (n >= M) return;
    int h = lane >> 4;
    float adv = ad[n * 4 + h];
    int start = rowptr[n], end = rowptr[n + 1];
    float acc0[4] = {0.f, 0.f, 0.f, 0.f}, acc1[4] = {0.f, 0.f, 0.f, 0.f};
    float den0 = 0.f, den1 = 0.f;
    int e = start;
    for (; e + 1 < end; e += 2) {
        int s0 = csr_src[e], s1 = csr_src[e + 1];
        uint2 v0 = *(const uint2*)(xpb + (size_t)s0 * 256 + lane * 4);
        uint2 v1 = *(const uint2*)(xpb + (size_t)s1 * 256 + lane * 4);
        float p0 = __expf(lrelu(as[s0 * 4 + h] + adv));
        float p1 = __expf(lrelu(as[s1 * 4 + h] + adv));
        den0 += p0; den1 += p1;
        acc0[0] += p0 * bflo(v0.x); acc0[1] += p0 * bfhi(v0.x);
        acc0[2] += p0 * bflo(v0.y); acc0[3] += p0 * bfhi(v0.y);
        acc1[0] += p1 * bflo(v1.x); acc1[1] += p1 * bfhi(v1.x);
        acc1[2] += p1 * bflo(v1.y); acc1[3] += p1 * bfhi(v1.y);
    }
    if (e < end) {
        int s0 = csr_src[e];
        uint2 v0 = *(const uint2*)(xpb + (size_t)s0 * 256 + lane * 4);
        float p0 = __expf(lrelu(as[s0 * 4 + h] + adv));
        den0 += p0;
        acc0[0] += p0 * bflo(v0.x); acc0[1] += p0 * bfhi(v0.x);
        acc0[2] += p0 * bflo(v0.y); acc0[3] += p0 * bfhi(v0.y);
    }
    float dinv = 1.f / (den0 + den1 + 1e-16f);
    const float4 bb = *(const float4*)(b1 + lane * 4);
    float o0 = fmaxf((acc0[0] + acc1[0]) * dinv + bb.x, 0.f);
    float o1 = fmaxf((acc0[1] + acc1[1]) * dinv + bb.y, 0.f);
    float o2 = fmaxf((acc0[2] + acc1[2]) * dinv + bb.z, 0.f);
    float o3 = fmaxf((acc0[3] + acc1[3]) * dinv + bb.w, 0.f);
    unsigned short q0 = f2bf(o0), q1 = f2bf(o1), q2 = f2bf(o2), q3 = f2bf(o3);
    uint2 H, L;
    H.x = (unsigned)q0 | ((unsigned)q1 << 16);
    H.y = (unsigned)q2 | ((unsigned)q3 << 16);
    L.x = (unsigned)f2bf(o0 - bf2f(q0)) | ((unsigned)f2bf(o1 - bf2f(q1)) << 16);
    L.y = (unsigned)f2bf(o2 - bf2f(q2)) | ((unsigned)f2bf(o3 - bf2f(q3)) << 16);
    *(uint2*)(h1h + (size_t)n * 256 + lane * 4) = H;
    *(uint2*)(h1l + (size_t)n * 256 + lane * 4) = L;
}

// gather layer 2 (1 head, C=64): 1 wave/node, 4 edge-groups of 16 lanes.
__global__ __launch_bounds__(256) void k_gather2(const unsigned short* __restrict__ xp2b,
                                                 const float* __restrict__ as, const float* __restrict__ ad,
                                                 const int* __restrict__ rowptr, const int* __restrict__ csr_src,
                                                 const float* __restrict__ b2, const float* __restrict__ Wc,
                                                 float* __restrict__ uv, int M) {
    int wv = threadIdx.x >> 6, lane = threadIdx.x & 63;
    int n = blockIdx.x * 4 + wv;
    if (n >= M) return;
    int g = lane >> 4, q = lane & 15;
    float adv = ad[n];
    int start = rowptr[n], end = rowptr[n + 1];
    float acc[4] = {0.f, 0.f, 0.f, 0.f};
    float den = 0.f;
    for (int e = start; e < end; e += 4) {
        int ee = e + g;
        bool ok = ee < end;
        int s = csr_src[ok ? ee : start];
        uint2 v = *(const uint2*)(xp2b + (size_t)s * 64 + q * 4);
        float pw = ok ? __expf(lrelu(as[s] + adv)) : 0.f;
        den += pw;
        acc[0] += pw * bflo(v.x); acc[1] += pw * bfhi(v.x);
        acc[2] += pw * bflo(v.y); acc[3] += pw * bfhi(v.y);
    }
#pragma unroll
    for (int j = 0; j < 4; j++) {
        acc[j] += __shfl_xor(acc[j], 16, 64);
        acc[j] += __shfl_xor(acc[j], 32, 64);
    }
    den += __shfl_xor(den, 16, 64);
    den += __shfl_xor(den, 32, 64);
    float dinv = 1.f / (den + 1e-16f);
    float pr[8] = {0.f, 0.f, 0.f, 0.f, 0.f, 0.f, 0.f, 0.f};
#pragma unroll
    for (int j = 0; j < 4; j++) {
        int c = q * 4 + j;
        float val = acc[j] * dinv + b2[c];
#pragma unroll
        for (int k = 0; k < 4; k++) {
            pr[k]     += val * Wc[c * 4 + k];
            pr[4 + k] += val * Wc[(64 + c) * 4 + k];
        }
    }
#pragma unroll
    for (int off = 1; off <= 8; off <<= 1)
#pragma unroll
        for (int j = 0; j < 8; j++) pr[j] += __shfl_xor(pr[j], off, 64);
    if (lane == 0) {
        float4* o = (float4*)(uv + (size_t)n * 8);
        o[0] = make_float4(pr[0], pr[1], pr[2], pr[3]);
        o[1] = make_float4(pr[4], pr[5], pr[6], pr[7]);
    }
}

__global__ __launch_bounds__(256) void k_classify(const int* __restrict__ ei, const float* __restrict__ uv,
                                                  const float* __restrict__ bc, float* __restrict__ out, int E) {
    int e = blockIdx.x * 256 + threadIdx.x;
    if (e >= E) return;
    int r = ei[e];
    int c = ei[E + e];
    float4 u = *(const float4*)(uv + (size_t)r * 8);
    float4 v = *(const float4*)(uv + (size_t)c * 8 + 4);
    float4 o;
    o.x = u.x + v.x + bc[0];
    o.y = u.y + v.y + bc[1];
    o.z = u.z + v.z + bc[2];
    o.w = u.w + v.w + bc[3];
    *(float4*)(out + (size_t)e * 4) = o;
}

// ---------------------------------------------------------------------------

extern "C" void kernel_launch(void* const* d_in, const int* in_sizes, int n_in,
                              void* d_out, int out_size, void* d_ws, size_t ws_size,
                              hipStream_t stream) {
    const float* x    = (const float*)d_in[0];
    const int*   ei   = (const int*)d_in[1];
    // d_in[2] = w (edge weights) ignored by reference
    const float* W1   = (const float*)d_in[3];
    const float* atS1 = (const float*)d_in[4];
    const float* atD1 = (const float*)d_in[5];
    const float* b1   = (const float*)d_in[6];
    const float* W2   = (const float*)d_in[7];
    const float* atS2 = (const float*)d_in[8];
    const float* atD2 = (const float*)d_in[9];
    const float* b2   = (const float*)d_in[10];
    const float* Wc   = (const float*)d_in[11];
    const float* bc   = (const float*)d_in[12];
    float* out = (float*)d_out;

    const int Nn = in_sizes[0] / 256;   // nodes
    const int E = in_sizes[1] / 2;
    const int Etot = E + Nn;
    const int NB = (Nn + 255) / 256;    // scan blocks

    char* w = (char*)d_ws;
    size_t off = 0;
    auto alloc = [&](size_t b) { size_t o = off; off = (o + b + 255) & ~(size_t)255; return o; };
    size_t oXH  = alloc((size_t)Nn * 256 * 2);   // x hi split; later h1h
    size_t oXL  = alloc((size_t)Nn * 256 * 2);   // x lo split; later h1l
    size_t oXPB = alloc((size_t)Nn * 256 * 2);   // xp bf16; later xp2b|uv
    size_t oAS1 = alloc((size_t)Nn * 4 * 4);
    size_t oAD1 = alloc((size_t)Nn * 4 * 4);
    size_t oDEG = alloc((size_t)Nn * 4);
    size_t oCUR = alloc((size_t)Nn * 4);
    size_t oRP  = alloc((size_t)(Nn + 1) * 4);
    size_t oCSR = alloc((size_t)Etot * 4);
    size_t oW1H = alloc((size_t)256 * 256 * 2);
    size_t oW1L = alloc((size_t)256 * 256 * 2);
    size_t oW2H = alloc((size_t)256 * 64 * 2);
    size_t oW2L = alloc((size_t)256 * 64 * 2);
    size_t oBS  = alloc((size_t)NB * 4);
    size_t oBO  = alloc((size_t)NB * 4);
    (void)ws_size;

    unsigned short* xh   = (unsigned short*)(w + oXH);
    unsigned short* xl   = (unsigned short*)(w + oXL);
    unsigned short* h1h  = (unsigned short*)(w + oXH);   // alias: xh dead after gemm1
    unsigned short* h1l  = (unsigned short*)(w + oXL);
    unsigned short* xpb  = (unsigned short*)(w + oXPB);
    unsigned short* xp2b = (unsigned short*)(w + oXPB);  // alias: xpb dead after gather1
    float* uv  = (float*)(w + oXPB + (size_t)Nn * 64 * 2 + 256);
    uv = (float*)(((uintptr_t)uv + 255) & ~(uintptr_t)255);
    float* as1 = (float*)(w + oAS1);
    float* ad1 = (float*)(w + oAD1);
    float* as2 = (float*)(w + oAS1);                     // alias: as1 dead after gather1
    float* ad2 = (float*)(w + oAD1);
    int* deg    = (int*)(w + oDEG);
    int* cur    = (int*)(w + oCUR);
    int* rowptr = (int*)(w + oRP);
    int* csr    = (int*)(w + oCSR);
    int* bsum   = (int*)(w + oBS);
    int* boff   = (int*)(w + oBO);
    unsigned short* W1hT = (unsigned short*)(w + oW1H);
    unsigned short* W1lT = (unsigned short*)(w + oW1L);
    unsigned short* W2hT = (unsigned short*)(w + oW2H);
    unsigned short* W2lT = (unsigned short*)(w + oW2L);

    // CSR build (parallel scan)
    k_init<<<NB, 256, 0, stream>>>(deg, cur, Nn);
    k_hist<<<(E + 255) / 256, 256, 0, stream>>>(ei, deg, E);
    k_bsum<<<NB, 256, 0, stream>>>(deg, bsum, Nn);
    k_bscan<<<1, 256, 0, stream>>>(bsum, boff, rowptr, NB, Nn);
    k_rowptr<<<NB, 256, 0, stream>>>(deg, boff, rowptr, Nn);
    k_scatter<<<(Etot + 255) / 256, 256, 0, stream>>>(ei, rowptr, cur, csr, E, Nn);

    // packing
    k_pack_split<<<2048, 256, 0, stream>>>(x, xh, xl, (long)Nn * 64);
    k_pack_wT<<<(256 * 256 + 255) / 256, 256, 0, stream>>>(W1, W1hT, W1lT, 256, 256);
    k_pack_wT<<<(256 * 64 + 255) / 256, 256, 0, stream>>>(W2, W2hT, W2lT, 256, 64);

    // Layer 1: 128x128 tile (WGM=2, WGN=2), grid.y = 256/128 = 2
    {
        dim3 g((Nn + 127) / 128, 2);
        k_gemm_lds<2, 2><<<g, 256, 0, stream>>>(xh, xl, W1hT, W1lT, xpb, Nn, 256, 256);
    }
    k_attn<<<(Nn * 4 + 255) / 256, 256, 0, stream>>>(xpb, atS1, atD1, as1, ad1, Nn, 4);
    k_gather1<<<(Nn + 3) / 4, 256, 0, stream>>>(xpb, as1, ad1, rowptr, csr, b1, h1h, h1l, Nn);

    // Layer 2: 256x64 tile (WGM=4, WGN=1), grid.y = 1
    {
        dim3 g((Nn + 255) / 256, 1);
        k_gemm_lds<4, 1><<<g, 256, 0, stream>>>(h1h, h1l, W2hT, W2lT, xp2b, Nn, 64, 256);
    }
    k_attn<<<(Nn + 255) / 256, 256, 0, stream>>>(xp2b, atS2, atD2, as2, ad2, Nn, 1);
    k_gather2<<<(Nn + 3) / 4, 256, 0, stream>>>(xp2b, as2, ad2, rowptr, csr, b2, Wc, uv, Nn);

    // Edge classifier
    k_classify<<<(E + 255) / 256, 256, 0, stream>>>(ei, uv, bc, out, E);
}

// Round 10
// 285.730 us; speedup vs baseline: 1.7330x; 1.1056x over previous
//
#include <hip/hip_runtime.h>

// ---------------------------------------------------------------------------
// GAT edge classifier, MI355X.
//   CSR build: deg hist -> 3-phase parallel scan -> scatter [int atomics only]
//   pack: x -> xh bf16 (A-side); W1,W2 -> transposed bf16 hi/lo splits
//   GEMM (m97 structure): global_load_lds width=16 staging, BK=64, 2-barrier
//     K-loop, XOR-swizzle both sides. 2-term split (ah*bh + ah*bl = bf16(A)*B).
//     Fused attention epilogue: per-wave head dot + 16-lane shfl reduce -> as/ad
//     (computed from f32 accs, more accurate than bf16 re-read).
//   gather1: 1 wave/node, 8B/lane, fused p=exp(lrelu(.)), 4-edge ILP -> h1 bf16
//   GEMM2 -> xp2b (+attn2 fused); gather2 (4-edge groups/wave, fused uv=h2@Wc)
//   classify: out[e] = u[row] + v[col] + bc
// ---------------------------------------------------------------------------

#define NEG 0.2f

typedef __attribute__((ext_vector_type(8))) short bf16x8;
typedef __attribute__((ext_vector_type(4))) float f32x4;

__device__ __forceinline__ unsigned short f2bf(float f) {
    unsigned int u = __float_as_uint(f);
    unsigned int r = (u + 0x7FFFu + ((u >> 16) & 1u)) >> 16;   // RNE
    return (unsigned short)r;
}
__device__ __forceinline__ float bf2f(unsigned short h) {
    return __uint_as_float(((unsigned int)h) << 16);
}
__device__ __forceinline__ float bflo(unsigned int u) { return __uint_as_float(u << 16); }
__device__ __forceinline__ float bfhi(unsigned int u) { return __uint_as_float(u & 0xFFFF0000u); }
__device__ __forceinline__ float lrelu(float x) { return x > 0.f ? x : NEG * x; }

// async global->LDS, 16 bytes per lane. Dest is wave-uniform base + lane*16.
__device__ __forceinline__ void async16(const void* g, void* l) {
    __builtin_amdgcn_global_load_lds(
        (const __attribute__((address_space(1))) unsigned int*)g,
        (__attribute__((address_space(3))) unsigned int*)l, 16, 0, 0);
}

// ------------------------------- CSR build --------------------------------

__global__ __launch_bounds__(256) void k_init(int* deg, int* cur, int n) {
    int i = blockIdx.x * 256 + threadIdx.x;
    if (i < n) { deg[i] = 1; cur[i] = 0; }  // deg starts at 1 for self-loop
}

__global__ __launch_bounds__(256) void k_hist(const int* __restrict__ ei, int* deg, int E) {
    int e = blockIdx.x * 256 + threadIdx.x;
    if (e < E) atomicAdd(&deg[ei[E + e]], 1);   // dst = ei[1][e]
}

__global__ __launch_bounds__(256) void k_bsum(const int* __restrict__ deg, int* __restrict__ bsum, int n) {
    int i = blockIdx.x * 256 + threadIdx.x;
    int v = (i < n) ? deg[i] : 0;
#pragma unroll
    for (int off = 1; off < 64; off <<= 1) v += __shfl_xor(v, off, 64);
    __shared__ int ws[4];
    int wv = threadIdx.x >> 6, l = threadIdx.x & 63;
    if (l == 0) ws[wv] = v;
    __syncthreads();
    if (threadIdx.x == 0) bsum[blockIdx.x] = ws[0] + ws[1] + ws[2] + ws[3];
}

// exclusive scan of bsum[0..nb), nb <= 256; also writes rowptr[n] = total
__global__ __launch_bounds__(256) void k_bscan(const int* __restrict__ bsum, int* __restrict__ boff,
                                               int* __restrict__ rowptr, int nb, int n) {
    __shared__ int s[256];
    int t = threadIdx.x;
    int v = (t < nb) ? bsum[t] : 0;
    s[t] = v;
    __syncthreads();
    for (int off = 1; off < 256; off <<= 1) {
        int u = (t >= off) ? s[t - off] : 0;
        __syncthreads();
        s[t] += u;
        __syncthreads();
    }
    if (t < nb) boff[t] = s[t] - v;
    if (t == nb - 1) rowptr[n] = s[t];
}

__global__ __launch_bounds__(256) void k_rowptr(const int* __restrict__ deg, const int* __restrict__ boff,
                                                int* __restrict__ rowptr, int n) {
    __shared__ int s[256];
    int i = blockIdx.x * 256 + threadIdx.x;
    int t = threadIdx.x;
    int v = (i < n) ? deg[i] : 0;
    s[t] = v;
    __syncthreads();
    for (int off = 1; off < 256; off <<= 1) {
        int u = (t >= off) ? s[t - off] : 0;
        __syncthreads();
        s[t] += u;
        __syncthreads();
    }
    if (i < n) rowptr[i] = boff[blockIdx.x] + s[t] - v;
}

__global__ __launch_bounds__(256) void k_scatter(const int* __restrict__ ei, const int* __restrict__ rowptr,
                                                 int* cur, int* csr_src, int E, int N) {
    int e = blockIdx.x * 256 + threadIdx.x;
    if (e < E) {
        int d = ei[E + e];
        int pos = rowptr[d] + atomicAdd(&cur[d], 1);
        csr_src[pos] = ei[e];
    } else if (e < E + N) {
        int i = e - E;  // self loop
        int pos = rowptr[i] + atomicAdd(&cur[i], 1);
        csr_src[pos] = i;
    }
}

// ------------------------------- packing ----------------------------------

// fp32 -> bf16 (A-side only needs hi; 2-term split keeps B in hi/lo)
__global__ __launch_bounds__(256) void k_pack_hi(const float* __restrict__ src,
                                                 unsigned short* __restrict__ hi, long n4) {
    long i = (long)blockIdx.x * 256 + threadIdx.x;
    long stride = (long)gridDim.x * 256;
    for (; i < n4; i += stride) {
        float4 v = ((const float4*)src)[i];
        ((ushort4*)hi)[i] = make_ushort4(f2bf(v.x), f2bf(v.y), f2bf(v.z), f2bf(v.w));
    }
}

// W [K,N] fp32 -> WT hi/lo bf16 [N,K]
__global__ __launch_bounds__(256) void k_pack_wT(const float* __restrict__ W,
                                                 unsigned short* __restrict__ hiT,
                                                 unsigned short* __restrict__ loT, int K, int N) {
    int t = blockIdx.x * 256 + threadIdx.x;
    if (t >= K * N) return;
    int n = t / K, k = t - n * K;
    float v = W[(size_t)k * N + n];
    unsigned short h = f2bf(v);
    hiT[t] = h;
    loT[t] = f2bf(v - bf2f(h));
}

// ------------------------------- MFMA GEMM (LDS, m97 structure) -----------
// C[M,N] = bf16(A)[M,K] @ B[K,N] (B as hi/lo bf16 [N,K], 2-term).
// Fused attn epilogue: wave owns one head's 64 cols -> as/ad row dots.
template<int WGM, int WGN>
__global__ __launch_bounds__(256, 2) void k_gemm_lds(const unsigned short* __restrict__ Ah,
                                                     const unsigned short* __restrict__ BhT,
                                                     const unsigned short* __restrict__ BlT,
                                                     unsigned short* __restrict__ Cb, int M, int N, int K,
                                                     const float* __restrict__ att_s,
                                                     const float* __restrict__ att_d,
                                                     float* __restrict__ as, float* __restrict__ ad, int H) {
    constexpr int BM = WGM * 64, BN = WGN * 64;
    __shared__ char lds[BM * 128 + BN * 256];      // Ah | Bh | Bl, rows*128B
    char* LAh = lds;
    char* LBh = lds + BM * 128;
    char* LBl = lds + BM * 128 + BN * 128;

    const int t = threadIdx.x, wv = t >> 6, l = t & 63;
    const int r = l & 15, hk = l >> 4;
    const int m0 = blockIdx.x * BM;
    const int n0 = blockIdx.y * BN;
    const int wr = wv / WGN, wc = wv % WGN;
    const int wrow0 = wr * 64, wcol0 = wc * 64;

    f32x4 acc[4][4];
#pragma unroll
    for (int i = 0; i < 4; i++)
#pragma unroll
        for (int j = 0; j < 4; j++) acc[i][j] = f32x4{0, 0, 0, 0};

    const int lrow8 = l >> 3;                       // 0..7
    const int cbs = ((l & 7) ^ lrow8) << 4;         // inverse-swizzled src col byte
    const size_t K2 = (size_t)K * 2;
    const int NCH = K >> 6;

    for (int c = 0; c < NCH; ++c) {
        const int kk2 = c * 128;
        {
            const int SA = BM / 8;
            for (int i = wv; i < SA; i += 4) {
                int row = i * 8 + lrow8;
                size_t go = (size_t)(m0 + row) * K2 + kk2 + cbs;
                async16((const char*)Ah + go, LAh + i * 1024);
            }
            const int SB = BN / 8;
            for (int i = wv; i < SB; i += 4) {
                int row = i * 8 + lrow8;
                size_t go = (size_t)(n0 + row) * K2 + kk2 + cbs;
                async16((const char*)BhT + go, LBh + i * 1024);
                async16((const char*)BlT + go, LBl + i * 1024);
            }
        }
        __syncthreads();
#pragma unroll
        for (int ks = 0; ks < 2; ++ks) {
            const int cb = ks * 64 + hk * 16;
            bf16x8 a_h[4], b_h[4], b_l[4];
#pragma unroll
            for (int fm = 0; fm < 4; ++fm) {
                int row = wrow0 + fm * 16 + r;
                int ad_ = row * 128 + (cb ^ ((row & 7) << 4));
                a_h[fm] = *(const bf16x8*)(LAh + ad_);
            }
#pragma unroll
            for (int fn = 0; fn < 4; ++fn) {
                int row = wcol0 + fn * 16 + r;
                int ad_ = row * 128 + (cb ^ ((row & 7) << 4));
                b_h[fn] = *(const bf16x8*)(LBh + ad_);
                b_l[fn] = *(const bf16x8*)(LBl + ad_);
            }
#pragma unroll
            for (int fm = 0; fm < 4; ++fm)
#pragma unroll
                for (int fn = 0; fn < 4; ++fn) {
                    acc[fm][fn] = __builtin_amdgcn_mfma_f32_16x16x32_bf16(a_h[fm], b_h[fn], acc[fm][fn], 0, 0, 0);
                    acc[fm][fn] = __builtin_amdgcn_mfma_f32_16x16x32_bf16(a_h[fm], b_l[fn], acc[fm][fn], 0, 0, 0);
                }
        }
        if (c + 1 < NCH) __syncthreads();
    }

    // ---- C write (C/D frag: col=lane&15, row=(lane>>4)*4+j) ----
#pragma unroll
    for (int fm = 0; fm < 4; ++fm)
#pragma unroll
        for (int fn = 0; fn < 4; ++fn)
#pragma unroll
            for (int j = 0; j < 4; ++j) {
                int m = m0 + wrow0 + fm * 16 + hk * 4 + j;
                if (m < M) Cb[(size_t)m * N + n0 + wcol0 + fn * 16 + r] = f2bf(acc[fm][fn][j]);
            }

    // ---- fused attention dots for this wave's head (from f32 accs) ----
    {
        int head = (n0 + wcol0) >> 6;
        float satt[4], datt[4];
#pragma unroll
        for (int fn = 0; fn < 4; ++fn) {
            satt[fn] = att_s[head * 64 + fn * 16 + r];
            datt[fn] = att_d[head * 64 + fn * 16 + r];
        }
#pragma unroll
        for (int fm = 0; fm < 4; ++fm)
#pragma unroll
            for (int j = 0; j < 4; ++j) {
                float ps = 0.f, pd = 0.f;
#pragma unroll
                for (int fn = 0; fn < 4; ++fn) {
                    ps += satt[fn] * acc[fm][fn][j];
                    pd += datt[fn] * acc[fm][fn][j];
                }
#pragma unroll
                for (int off = 1; off <= 8; off <<= 1) {
                    ps += __shfl_xor(ps, off, 64);
                    pd += __shfl_xor(pd, off, 64);
                }
                if (r == 0) {
                    int m = m0 + wrow0 + fm * 16 + hk * 4 + j;
                    if (m < M) { as[m * H + head] = ps; ad[m * H + head] = pd; }
                }
            }
    }
}

// ------------------------------- gathers ----------------------------------

// gather layer 1: 1 wave/node, lane owns 4 cols (8B), head h=lane>>4.
// p computed inline (no max-sub: raw is O(3), exp safe in fp32). 4-edge ILP.
__global__ __launch_bounds__(256) void k_gather1(const unsigned short* __restrict__ xpb,
                                                 const float* __restrict__ as, const float* __restrict__ ad,
                                                 const int* __restrict__ rowptr, const int* __restrict__ csr_src,
                                                 const float* __restrict__ b1,
                                                 unsigned short* __restrict__ h1h, int M) {
    int wv = threadIdx.x >> 6, lane = threadIdx.x & 63;
    int n = blockIdx.x * 4 + wv;
    if (n >= M) return;
    int h = lane >> 4;
    float adv = ad[n * 4 + h];
    int start = rowptr[n], end = rowptr[n + 1];
    float a0[4] = {0.f, 0.f, 0.f, 0.f}, a1[4] = {0.f, 0.f, 0.f, 0.f};
    float den0 = 0.f, den1 = 0.f;
    int e = start;
    for (; e + 3 < end; e += 4) {
        int s0 = csr_src[e], s1 = csr_src[e + 1], s2 = csr_src[e + 2], s3 = csr_src[e + 3];
        uint2 v0 = *(const uint2*)(xpb + (size_t)s0 * 256 + lane * 4);
        uint2 v1 = *(const uint2*)(xpb + (size_t)s1 * 256 + lane * 4);
        uint2 v2 = *(const uint2*)(xpb + (size_t)s2 * 256 + lane * 4);
        uint2 v3 = *(const uint2*)(xpb + (size_t)s3 * 256 + lane * 4);
        float w0 = as[s0 * 4 + h], w1 = as[s1 * 4 + h], w2 = as[s2 * 4 + h], w3 = as[s3 * 4 + h];
        float p0 = __expf(lrelu(w0 + adv));
        float p1 = __expf(lrelu(w1 + adv));
        float p2 = __expf(lrelu(w2 + adv));
        float p3 = __expf(lrelu(w3 + adv));
        den0 += p0 + p2; den1 += p1 + p3;
        a0[0] += p0 * bflo(v0.x); a0[1] += p0 * bfhi(v0.x);
        a0[2] += p0 * bflo(v0.y); a0[3] += p0 * bfhi(v0.y);
        a1[0] += p1 * bflo(v1.x); a1[1] += p1 * bfhi(v1.x);
        a1[2] += p1 * bflo(v1.y); a1[3] += p1 * bfhi(v1.y);
        a0[0] += p2 * bflo(v2.x); a0[1] += p2 * bfhi(v2.x);
        a0[2] += p2 * bflo(v2.y); a0[3] += p2 * bfhi(v2.y);
        a1[0] += p3 * bflo(v3.x); a1[1] += p3 * bfhi(v3.x);
        a1[2] += p3 * bflo(v3.y); a1[3] += p3 * bfhi(v3.y);
    }
    for (; e < end; ++e) {
        int s0 = csr_src[e];
        uint2 v0 = *(const uint2*)(xpb + (size_t)s0 * 256 + lane * 4);
        float p0 = __expf(lrelu(as[s0 * 4 + h] + adv));
        den0 += p0;
        a0[0] += p0 * bflo(v0.x); a0[1] += p0 * bfhi(v0.x);
        a0[2] += p0 * bflo(v0.y); a0[3] += p0 * bfhi(v0.y);
    }
    float dinv = 1.f / (den0 + den1 + 1e-16f);
    const float4 bb = *(const float4*)(b1 + lane * 4);
    float o0 = fmaxf((a0[0] + a1[0]) * dinv + bb.x, 0.f);
    float o1 = fmaxf((a0[1] + a1[1]) * dinv + bb.y, 0.f);
    float o2 = fmaxf((a0[2] + a1[2]) * dinv + bb.z, 0.f);
    float o3 = fmaxf((a0[3] + a1[3]) * dinv + bb.w, 0.f);
    uint2 H;
    H.x = (unsigned)f2bf(o0) | ((unsigned)f2bf(o1) << 16);
    H.y = (unsigned)f2bf(o2) | ((unsigned)f2bf(o3) << 16);
    *(uint2*)(h1h + (size_t)n * 256 + lane * 4) = H;
}

// gather layer 2 (1 head, C=64): 1 wave/node, 4 edge-groups of 16 lanes.
__global__ __launch_bounds__(256) void k_gather2(const unsigned short* __restrict__ xp2b,
                                                 const float* __restrict__ as, const float* __restrict__ ad,
                                                 const int* __restrict__ rowptr, const int* __restrict__ csr_src,
                                                 const float* __restrict__ b2, const float* __restrict__ Wc,
                                                 float* __restrict__ uv, int M) {
    int wv = threadIdx.x >> 6, lane = threadIdx.x & 63;
    int n = blockIdx.x * 4 + wv;
    if (n >= M) return;
    int g = lane >> 4, q = lane & 15;
    float adv = ad[n];
    int start = rowptr[n], end = rowptr[n + 1];
    float acc[4] = {0.f, 0.f, 0.f, 0.f};
    float den = 0.f;
    for (int e = start; e < end; e += 4) {
        int ee = e + g;
        bool ok = ee < end;
        int s = csr_src[ok ? ee : start];
        uint2 v = *(const uint2*)(xp2b + (size_t)s * 64 + q * 4);
        float pw = ok ? __expf(lrelu(as[s] + adv)) : 0.f;
        den += pw;
        acc[0] += pw * bflo(v.x); acc[1] += pw * bfhi(v.x);
        acc[2] += pw * bflo(v.y); acc[3] += pw * bfhi(v.y);
    }
#pragma unroll
    for (int j = 0; j < 4; j++) {
        acc[j] += __shfl_xor(acc[j], 16, 64);
        acc[j] += __shfl_xor(acc[j], 32, 64);
    }
    den += __shfl_xor(den, 16, 64);
    den += __shfl_xor(den, 32, 64);
    float dinv = 1.f / (den + 1e-16f);
    float pr[8] = {0.f, 0.f, 0.f, 0.f, 0.f, 0.f, 0.f, 0.f};
#pragma unroll
    for (int j = 0; j < 4; j++) {
        int c = q * 4 + j;
        float val = acc[j] * dinv + b2[c];
#pragma unroll
        for (int k = 0; k < 4; k++) {
            pr[k]     += val * Wc[c * 4 + k];
            pr[4 + k] += val * Wc[(64 + c) * 4 + k];
        }
    }
#pragma unroll
    for (int off = 1; off <= 8; off <<= 1)
#pragma unroll
        for (int j = 0; j < 8; j++) pr[j] += __shfl_xor(pr[j], off, 64);
    if (lane == 0) {
        float4* o = (float4*)(uv + (size_t)n * 8);
        o[0] = make_float4(pr[0], pr[1], pr[2], pr[3]);
        o[1] = make_float4(pr[4], pr[5], pr[6], pr[7]);
    }
}

__global__ __launch_bounds__(256) void k_classify(const int* __restrict__ ei, const float* __restrict__ uv,
                                                  const float* __restrict__ bc, float* __restrict__ out, int E) {
    int e = blockIdx.x * 256 + threadIdx.x;
    if (e >= E) return;
    int r = ei[e];
    int c = ei[E + e];
    float4 u = *(const float4*)(uv + (size_t)r * 8);
    float4 v = *(const float4*)(uv + (size_t)c * 8 + 4);
    float4 o;
    o.x = u.x + v.x + bc[0];
    o.y = u.y + v.y + bc[1];
    o.z = u.z + v.z + bc[2];
    o.w = u.w + v.w + bc[3];
    *(float4*)(out + (size_t)e * 4) = o;
}

// ---------------------------------------------------------------------------

extern "C" void kernel_launch(void* const* d_in, const int* in_sizes, int n_in,
                              void* d_out, int out_size, void* d_ws, size_t ws_size,
                              hipStream_t stream) {
    const float* x    = (const float*)d_in[0];
    const int*   ei   = (const int*)d_in[1];
    // d_in[2] = w (edge weights) ignored by reference
    const float* W1   = (const float*)d_in[3];
    const float* atS1 = (const float*)d_in[4];
    const float* atD1 = (const float*)d_in[5];
    const float* b1   = (const float*)d_in[6];
    const float* W2   = (const float*)d_in[7];
    const float* atS2 = (const float*)d_in[8];
    const float* atD2 = (const float*)d_in[9];
    const float* b2   = (const float*)d_in[10];
    const float* Wc   = (const float*)d_in[11];
    const float* bc   = (const float*)d_in[12];
    float* out = (float*)d_out;

    const int Nn = in_sizes[0] / 256;   // nodes
    const int E = in_sizes[1] / 2;
    const int Etot = E + Nn;
    const int NB = (Nn + 255) / 256;    // scan blocks

    char* w = (char*)d_ws;
    size_t off = 0;
    auto alloc = [&](size_t b) { size_t o = off; off = (o + b + 255) & ~(size_t)255; return o; };
    size_t oXH  = alloc((size_t)Nn * 256 * 2);   // x bf16; later h1h
    size_t oXPB = alloc((size_t)Nn * 256 * 2);   // xp bf16; later xp2b|uv
    size_t oAS1 = alloc((size_t)Nn * 4 * 4);
    size_t oAD1 = alloc((size_t)Nn * 4 * 4);
    size_t oDEG = alloc((size_t)Nn * 4);
    size_t oCUR = alloc((size_t)Nn * 4);
    size_t oRP  = alloc((size_t)(Nn + 1) * 4);
    size_t oCSR = alloc((size_t)Etot * 4);
    size_t oW1H = alloc((size_t)256 * 256 * 2);
    size_t oW1L = alloc((size_t)256 * 256 * 2);
    size_t oW2H = alloc((size_t)256 * 64 * 2);
    size_t oW2L = alloc((size_t)256 * 64 * 2);
    size_t oBS  = alloc((size_t)NB * 4);
    size_t oBO  = alloc((size_t)NB * 4);
    (void)ws_size;

    unsigned short* xh   = (unsigned short*)(w + oXH);
    unsigned short* h1h  = (unsigned short*)(w + oXH);   // alias: xh dead after gemm1
    unsigned short* xpb  = (unsigned short*)(w + oXPB);
    unsigned short* xp2b = (unsigned short*)(w + oXPB);  // alias: xpb dead after gather1
    float* uv  = (float*)(w + oXPB + (size_t)Nn * 64 * 2 + 256);
    uv = (float*)(((uintptr_t)uv + 255) & ~(uintptr_t)255);
    float* as1 = (float*)(w + oAS1);
    float* ad1 = (float*)(w + oAD1);
    float* as2 = (float*)(w + oAS1);                     // alias: as1 dead after gather1
    float* ad2 = (float*)(w + oAD1);
    int* deg    = (int*)(w + oDEG);
    int* cur    = (int*)(w + oCUR);
    int* rowptr = (int*)(w + oRP);
    int* csr    = (int*)(w + oCSR);
    int* bsum   = (int*)(w + oBS);
    int* boff   = (int*)(w + oBO);
    unsigned short* W1hT = (unsigned short*)(w + oW1H);
    unsigned short* W1lT = (unsigned short*)(w + oW1L);
    unsigned short* W2hT = (unsigned short*)(w + oW2H);
    unsigned short* W2lT = (unsigned short*)(w + oW2L);

    // CSR build (parallel scan)
    k_init<<<NB, 256, 0, stream>>>(deg, cur, Nn);
    k_hist<<<(E + 255) / 256, 256, 0, stream>>>(ei, deg, E);
    k_bsum<<<NB, 256, 0, stream>>>(deg, bsum, Nn);
    k_bscan<<<1, 256, 0, stream>>>(bsum, boff, rowptr, NB, Nn);
    k_rowptr<<<NB, 256, 0, stream>>>(deg, boff, rowptr, Nn);
    k_scatter<<<(Etot + 255) / 256, 256, 0, stream>>>(ei, rowptr, cur, csr, E, Nn);

    // packing
    k_pack_hi<<<2048, 256, 0, stream>>>(x, xh, (long)Nn * 64);
    k_pack_wT<<<(256 * 256 + 255) / 256, 256, 0, stream>>>(W1, W1hT, W1lT, 256, 256);
    k_pack_wT<<<(256 * 64 + 255) / 256, 256, 0, stream>>>(W2, W2hT, W2lT, 256, 64);

    // Layer 1: 128x128 tile (WGM=2, WGN=2), grid.y = 2; attn fused
    {
        dim3 g((Nn + 127) / 128, 2);
        k_gemm_lds<2, 2><<<g, 256, 0, stream>>>(xh, W1hT, W1lT, xpb, Nn, 256, 256,
                                                atS1, atD1, as1, ad1, 4);
    }
    k_gather1<<<(Nn + 3) / 4, 256, 0, stream>>>(xpb, as1, ad1, rowptr, csr, b1, h1h, Nn);

    // Layer 2: 256x64 tile (WGM=4, WGN=1), grid.y = 1; attn fused
    {
        dim3 g((Nn + 255) / 256, 1);
        k_gemm_lds<4, 1><<<g, 256, 0, stream>>>(h1h, W2hT, W2lT, xp2b, Nn, 64, 256,
                                                atS2, atD2, as2, ad2, 1);
    }
    k_gather2<<<(Nn + 3) / 4, 256, 0, stream>>>(xp2b, as2, ad2, rowptr, csr, b2, Wc, uv, Nn);

    // Edge classifier
    k_classify<<<(E + 255) / 256, 256, 0, stream>>>(ei, uv, bc, out, E);
}